// Round 17
// baseline (179.507 us; speedup 1.0000x reference)
//
#include <hip/hip_runtime.h>
#include <math.h>

// Problem constants (from reference setup_inputs)
#define BB    8
#define DIN   1024
#define TT    2048
#define DCB   64
#define VV    8192
#define NN    (BB * TT)      // 16384 rows
#define EPSN  1e-12f

#define DSPLIT 4
#define CPCHUNK (VV / DSPLIT)    // 2048 codes per chunk
#define TSTEPS  (CPCHUNK / 32)   // 64 tiles of 32 codes

typedef float f32x4  __attribute__((ext_vector_type(4)));
typedef float f32x16 __attribute__((ext_vector_type(16)));
typedef int   i32x16 __attribute__((ext_vector_type(16)));
typedef _Float16 half8 __attribute__((ext_vector_type(8)));

typedef const __attribute__((address_space(1))) void* gas_ptr;
typedef __attribute__((address_space(3))) void* las_ptr;

// ---------------------------------------------------------------------------
// Kernel 1: normalize codebook rows; emit split-f16 ch (hi), cl (2048*lo),
// and c2 = sum(cn*cn) per row (f32, mirrors reference cn2).
// ---------------------------------------------------------------------------
__global__ void __launch_bounds__(256) k_prep_cb(const float* __restrict__ cb,
                                                 _Float16* __restrict__ ch,
                                                 _Float16* __restrict__ cl,
                                                 float* __restrict__ c2) {
    int v    = blockIdx.x * 4 + (threadIdx.x >> 6);
    int k    = threadIdx.x & 63;
    float x  = cb[v * DCB + k];
    float s  = x * x;
    #pragma unroll
    for (int off = 32; off; off >>= 1) s += __shfl_xor(s, off, 64);
    float den = fmaxf(sqrtf(s), EPSN);
    float c   = x / den;

    _Float16 h = (_Float16)c;
    float r    = c - (float)h;
    ch[v * DCB + k] = h;
    cl[v * DCB + k] = (_Float16)(r * 2048.0f);

    float s2 = c * c;
    #pragma unroll
    for (int off = 32; off; off >>= 1) s2 += __shfl_xor(s2, off, 64);
    if (k == 0) c2[v] = s2;
}

// ---------------------------------------------------------------------------
// Kernel 2: transpose W [DCB, DIN] -> wt [DIN, DCB]
// ---------------------------------------------------------------------------
__global__ void __launch_bounds__(256) k_prep_wt(const float* __restrict__ W,
                                                 float* __restrict__ wt) {
    int i = blockIdx.x * 256 + threadIdx.x;
    int d = i >> 10;
    int c = i & 1023;
    wt[c * DCB + d] = W[d * DIN + c];
}

// ---------------------------------------------------------------------------
// Kernel 3a: partial projection GEMM, runtime K-split (R10 exact).
// ---------------------------------------------------------------------------
__global__ void __launch_bounds__(256, 2)
k_gemm_part(const float* __restrict__ z, const float* __restrict__ wt,
            float* __restrict__ part, int kch) {
    __shared__ __align__(1024) float wlds[256 * 64];  // up to 64 KB (kch<=256)

    int tid  = threadIdx.x;
    int lane = tid & 63;
    int wv   = tid >> 6;         // 0..3
    int d0   = wv * 16;
    int n0   = blockIdx.x * 256; // 256 rows (t) per block
    int ks   = blockIdx.y;
    int c0   = ks * kch;
    int b    = n0 >> 11;
    int t0   = (n0 & 2047) + lane * 4;

    {
        const f32x4* wsrc = (const f32x4*)(wt + (size_t)c0 * DCB);
        int ncalls = kch / 16;
        for (int k = 0; k < ncalls; ++k) {
            int ub = k * 256 + wv * 64;
            __builtin_amdgcn_global_load_lds((gas_ptr)(wsrc + ub + lane),
                                             (las_ptr)((f32x4*)wlds + ub), 16, 0, 0);
        }
    }
    asm volatile("s_waitcnt vmcnt(0)" ::: "memory");
    __syncthreads();

    const float* zp = z + (size_t)b * (DIN * TT) + (size_t)c0 * TT + t0;

    f32x4 acc[4][4];
    #pragma unroll
    for (int i = 0; i < 4; ++i)
        #pragma unroll
        for (int j = 0; j < 4; ++j) acc[i][j] = (f32x4)0.0f;

    #pragma unroll 8
    for (int c = 0; c < kch; ++c) {
        f32x4 zv = *(const f32x4*)(zp + (size_t)c * TT);
        const f32x4* wr = (const f32x4*)&wlds[c * DCB + d0];
        f32x4 w0 = wr[0], w1 = wr[1], w2 = wr[2], w3 = wr[3];
        #pragma unroll
        for (int tq = 0; tq < 4; ++tq) {
            float zs = zv[tq];
            acc[tq][0] += w0 * zs;
            acc[tq][1] += w1 * zs;
            acc[tq][2] += w2 * zs;
            acc[tq][3] += w3 * zs;
        }
    }

    float* pp = part + ((size_t)ks * NN + n0 + lane * 4) * DCB + d0;
    #pragma unroll
    for (int tq = 0; tq < 4; ++tq) {
        f32x4* dst = (f32x4*)(pp + (size_t)tq * DCB);
        dst[0] = acc[tq][0];
        dst[1] = acc[tq][1];
        dst[2] = acc[tq][2];
        dst[3] = acc[tq][3];
    }
}

// ---------------------------------------------------------------------------
// Kernel 3b: combine partials + bias, L2-normalize rows, emit split-f16.
// ---------------------------------------------------------------------------
__global__ void __launch_bounds__(256) k_combine(const float* __restrict__ part,
                                                 const float* __restrict__ bias,
                                                 _Float16* __restrict__ eh,
                                                 _Float16* __restrict__ el,
                                                 int ksplit) {
    int gid = blockIdx.x * 256 + threadIdx.x;  // 0..131071
    int n   = gid >> 3;
    int d0  = (gid & 7) * 8;

    float ze[8];
    #pragma unroll
    for (int j = 0; j < 8; ++j) ze[j] = bias[d0 + j];

    for (int ks = 0; ks < ksplit; ++ks) {
        const float4* pp = (const float4*)(part + ((size_t)ks * NN + n) * DCB + d0);
        float4 p0 = pp[0], p1 = pp[1];
        ze[0] += p0.x; ze[1] += p0.y; ze[2] += p0.z; ze[3] += p0.w;
        ze[4] += p1.x; ze[5] += p1.y; ze[6] += p1.z; ze[7] += p1.w;
    }

    float ss = 0.0f;
    #pragma unroll
    for (int j = 0; j < 8; ++j) ss = fmaf(ze[j], ze[j], ss);
    ss += __shfl_xor(ss, 1, 64);
    ss += __shfl_xor(ss, 2, 64);
    ss += __shfl_xor(ss, 4, 64);
    float den = fmaxf(sqrtf(ss), EPSN);

    half8 vh, vl;
    #pragma unroll
    for (int j = 0; j < 8; ++j) {
        float x = ze[j] / den;
        _Float16 h = (_Float16)x;
        vh[j] = h;
        vl[j] = (_Float16)((x - (float)h) * 2048.0f);
    }
    *(half8*)&eh[(size_t)n * DCB + d0] = vh;
    *(half8*)&el[(size_t)n * DCB + d0] = vl;
}

// ---------------------------------------------------------------------------
// Kernel 4: fused split-f16 MFMA GEMM + argmax — NO-LDS variant.
// Codebook (2 MB split-f16) is L2-resident; B-fragments are loaded straight
// from global (base + imm offsets 0/32/64/96) — the L2 does the broadcast
// LDS used to do. Zero barriers, zero staging, zero bank conflicts; the
// compiler software-pipelines loads across tiles (no sync points).
// MFMA chain order identical to R10 -> bit-identical scores.
// ---------------------------------------------------------------------------
__global__ void __launch_bounds__(256)
k_distmax(const _Float16* __restrict__ eh, const _Float16* __restrict__ el,
          const _Float16* __restrict__ chg, const _Float16* __restrict__ clg,
          const float* __restrict__ c2,
          float* __restrict__ pscore, int* __restrict__ pidx) {
    int tid  = threadIdx.x;
    int w    = tid >> 6;
    int lane = tid & 63;
    int rr   = lane & 31;   // A: row slot / B: code slot / C: col
    int hhf  = lane >> 5;   // k-half selector
    int chunk = blockIdx.y;
    int v0   = chunk * CPCHUNK;
    int m0   = blockIdx.x * 128 + w * 32;

    // ---- A-frags: en row (m0+rr), split hi/lo, 4 K-chunks each ----
    const char* ehp = (const char*)(eh + (size_t)(m0 + rr) * DCB) + hhf * 16;
    const char* elp = (const char*)(el + (size_t)(m0 + rr) * DCB) + hhf * 16;
    half8 ah0 = *(const half8*)(ehp +  0), ah1 = *(const half8*)(ehp + 32);
    half8 ah2 = *(const half8*)(ehp + 64), ah3 = *(const half8*)(ehp + 96);
    half8 al0 = *(const half8*)(elp +  0), al1 = *(const half8*)(elp + 32);
    half8 al2 = *(const half8*)(elp + 64), al3 = *(const half8*)(elp + 96);
    asm volatile("" : "+v"(ah0), "+v"(ah1), "+v"(ah2), "+v"(ah3),
                      "+v"(al0), "+v"(al1), "+v"(al2), "+v"(al3));

    // ---- B row base for this lane's code slot (advances 4 KB per tile) ----
    const char* chp = (const char*)chg + ((size_t)(v0 + rr)) * 128 + hhf * 16;
    const char* clp = (const char*)clg + ((size_t)(v0 + rr)) * 128 + hhf * 16;

    f32x16 kz;
    f32x16 best;
    i32x16 bidx;
    #pragma unroll
    for (int i = 0; i < 16; ++i) { kz[i] = 0.0f; best[i] = -INFINITY; bidx[i] = 0; }

    #pragma unroll 2
    for (int t = 0; t < TSTEPS; ++t) {
        const char* bh = chp + (size_t)t * (32 * 128);
        const char* bl = clp + (size_t)t * (32 * 128);

        half8 bh0 = *(const half8*)(bh +  0);
        half8 bh1 = *(const half8*)(bh + 32);
        half8 bh2 = *(const half8*)(bh + 64);
        half8 bh3 = *(const half8*)(bh + 96);
        half8 bl0 = *(const half8*)(bl +  0);
        half8 bl1 = *(const half8*)(bl + 32);
        half8 bl2 = *(const half8*)(bl + 64);
        half8 bl3 = *(const half8*)(bl + 96);

        int   vcode = v0 + t * 32 + rr;
        float c2v   = c2[vcode];

        f32x16 Ahh, Amid;
        Ahh  = __builtin_amdgcn_mfma_f32_32x32x16_f16(ah0, bh0, kz, 0, 0, 0);
        Amid = __builtin_amdgcn_mfma_f32_32x32x16_f16(ah0, bl0, kz, 0, 0, 0);
        Amid = __builtin_amdgcn_mfma_f32_32x32x16_f16(al0, bh0, Amid, 0, 0, 0);
        Ahh  = __builtin_amdgcn_mfma_f32_32x32x16_f16(ah1, bh1, Ahh, 0, 0, 0);
        Amid = __builtin_amdgcn_mfma_f32_32x32x16_f16(ah1, bl1, Amid, 0, 0, 0);
        Amid = __builtin_amdgcn_mfma_f32_32x32x16_f16(al1, bh1, Amid, 0, 0, 0);
        Ahh  = __builtin_amdgcn_mfma_f32_32x32x16_f16(ah2, bh2, Ahh, 0, 0, 0);
        Amid = __builtin_amdgcn_mfma_f32_32x32x16_f16(ah2, bl2, Amid, 0, 0, 0);
        Amid = __builtin_amdgcn_mfma_f32_32x32x16_f16(al2, bh2, Amid, 0, 0, 0);
        Ahh  = __builtin_amdgcn_mfma_f32_32x32x16_f16(ah3, bh3, Ahh, 0, 0, 0);
        Amid = __builtin_amdgcn_mfma_f32_32x32x16_f16(ah3, bl3, Amid, 0, 0, 0);
        Amid = __builtin_amdgcn_mfma_f32_32x32x16_f16(al3, bh3, Amid, 0, 0, 0);

        #pragma unroll
        for (int i = 0; i < 16; ++i) {
            float dot = fmaf(Amid[i], 4.8828125e-4f, Ahh[i]);  // hh + mid/2048
            float s   = fmaf(2.0f, dot, -c2v);                 // 2*dot - cn2
            bool  g   = s > best[i];
            best[i]   = g ? s : best[i];
            bidx[i]   = g ? vcode : bidx[i];
        }
    }

    // ---- cross-lane argmax per output row (32 lanes share a row-set) ----
    #pragma unroll
    for (int i = 0; i < 16; ++i) {
        float bv = best[i];
        int   bi = bidx[i];
        #pragma unroll
        for (int off = 1; off < 32; off <<= 1) {
            float ob = __shfl_xor(bv, off, 64);
            int   oi = __shfl_xor(bi, off, 64);
            if (ob > bv || (ob == bv && oi < bi)) { bv = ob; bi = oi; }
        }
        if (rr == 0) {
            int row = m0 + (i & 3) + 8 * (i >> 2) + 4 * hhf;
            pscore[(size_t)chunk * NN + row] = bv;
            pidx  [(size_t)chunk * NN + row] = bi;
        }
    }
}

// ---------------------------------------------------------------------------
// Kernel 5: combine per-chunk winners (ascending chunk order preserves
// first-index tie-break). Output dtype is int32.
// ---------------------------------------------------------------------------
__global__ void __launch_bounds__(256) k_reduce(const float* __restrict__ pscore,
                                                const int* __restrict__ pidx,
                                                int* __restrict__ out) {
    int n = blockIdx.x * 256 + threadIdx.x;
    float best = -INFINITY;
    int   bi   = 0;
    #pragma unroll
    for (int c = 0; c < DSPLIT; ++c) {
        float s = pscore[(size_t)c * NN + n];
        int  id = pidx [(size_t)c * NN + n];
        if (s > best) { best = s; bi = id; }
    }
    out[n] = bi;
}

// ---------------------------------------------------------------------------
extern "C" void kernel_launch(void* const* d_in, const int* in_sizes, int n_in,
                              void* d_out, int out_size, void* d_ws, size_t ws_size,
                              hipStream_t stream) {
    const float* z  = (const float*)d_in[0];  // [8,1024,2048]
    const float* W  = (const float*)d_in[1];  // [64,1024]
    const float* bi = (const float*)d_in[2];  // [64]
    const float* cb = (const float*)d_in[3];  // [8192,64]
    int* out = (int*)d_out;                   // [16384] indices, int32

    char* ws = (char*)d_ws;
    _Float16* ch  = (_Float16*)(ws);                         // 1 MB
    _Float16* cl  = (_Float16*)(ws + 1048576);               // 1 MB
    float*    c2  = (float*)   (ws + 2097152);               // 32 KB
    float*    wt  = (float*)   (ws + 2129920);               // 256 KB
    _Float16* eh  = (_Float16*)(ws + 2392064);               // 2 MB
    _Float16* el  = (_Float16*)(ws + 4489216);               // 2 MB
    float* pscore = (float*)   (ws + 6586368);               // 256 KB
    int*   pidx   = (int*)     (ws + 6848512);               // 256 KB
    float* part   = (float*)   (ws + 7110656);               // 16 or 32 MB

    // Deterministic per-environment: ws_size is fixed, so ksplit is fixed.
    const size_t need8 = 7110656ULL + (size_t)8 * NN * DCB * 4;  // 40,665,088
    int ksplit = (ws_size >= need8) ? 8 : 4;
    int kch    = DIN / ksplit;

    hipLaunchKernelGGL(k_prep_cb,   dim3(VV / 4),          dim3(256), 0, stream, cb, ch, cl, c2);
    hipLaunchKernelGGL(k_prep_wt,   dim3(DIN * DCB / 256), dim3(256), 0, stream, W, wt);
    hipLaunchKernelGGL(k_gemm_part, dim3(NN / 256, ksplit), dim3(256), 0, stream, z, wt, part, kch);
    hipLaunchKernelGGL(k_combine,   dim3(NN * 8 / 256),    dim3(256), 0, stream, part, bi, eh, el, ksplit);
    hipLaunchKernelGGL(k_distmax,   dim3(NN / 128, DSPLIT), dim3(256), 0, stream,
                       eh, el, ch, cl, c2, pscore, pidx);
    hipLaunchKernelGGL(k_reduce,    dim3(NN / 256),        dim3(256), 0, stream, pscore, pidx, out);
}

// Round 18
// 121.383 us; speedup vs baseline: 1.4789x; 1.4789x over previous
//
#include <hip/hip_runtime.h>
#include <math.h>

// Problem constants (from reference setup_inputs)
#define BB    8
#define DIN   1024
#define TT    2048
#define DCB   64
#define VV    8192
#define NN    (BB * TT)      // 16384 rows
#define EPSN  1e-12f

#define DSPLIT 4
#define CPCHUNK (VV / DSPLIT)    // 2048 codes per chunk
#define TCODES 32                // codes per LDS tile (8 KB/tile)
#define TSTEPS  (CPCHUNK / TCODES)

typedef float f32x4  __attribute__((ext_vector_type(4)));
typedef float f32x16 __attribute__((ext_vector_type(16)));
typedef int   i32x16 __attribute__((ext_vector_type(16)));
typedef _Float16 half8 __attribute__((ext_vector_type(8)));

typedef const __attribute__((address_space(1))) void* gas_ptr;
typedef __attribute__((address_space(3))) void* las_ptr;

// ---------------------------------------------------------------------------
// Kernel 1: normalize codebook rows; emit split-f16 ch (hi), cl (2048*lo),
// and c2 = sum(cn*cn) per row (f32, mirrors reference cn2).
// ---------------------------------------------------------------------------
__global__ void __launch_bounds__(256) k_prep_cb(const float* __restrict__ cb,
                                                 _Float16* __restrict__ ch,
                                                 _Float16* __restrict__ cl,
                                                 float* __restrict__ c2) {
    int v    = blockIdx.x * 4 + (threadIdx.x >> 6);
    int k    = threadIdx.x & 63;
    float x  = cb[v * DCB + k];
    float s  = x * x;
    #pragma unroll
    for (int off = 32; off; off >>= 1) s += __shfl_xor(s, off, 64);
    float den = fmaxf(sqrtf(s), EPSN);
    float c   = x / den;

    _Float16 h = (_Float16)c;
    float r    = c - (float)h;
    ch[v * DCB + k] = h;
    cl[v * DCB + k] = (_Float16)(r * 2048.0f);

    float s2 = c * c;
    #pragma unroll
    for (int off = 32; off; off >>= 1) s2 += __shfl_xor(s2, off, 64);
    if (k == 0) c2[v] = s2;
}

// ---------------------------------------------------------------------------
// Kernel 2: transpose W [DCB, DIN] -> wt [DIN, DCB]
// ---------------------------------------------------------------------------
__global__ void __launch_bounds__(256) k_prep_wt(const float* __restrict__ W,
                                                 float* __restrict__ wt) {
    int i = blockIdx.x * 256 + threadIdx.x;
    int d = i >> 10;
    int c = i & 1023;
    wt[c * DCB + d] = W[d * DIN + c];
}

// ---------------------------------------------------------------------------
// Kernel 3a: partial projection GEMM, runtime K-split.
// lane <-> t (wave z-load = 1 KB contiguous), wave <-> d (weights from LDS
// via uniform broadcast ds_read_b128). 16 f32x4 accumulators; unroll 8.
// ---------------------------------------------------------------------------
__global__ void __launch_bounds__(256, 2)
k_gemm_part(const float* __restrict__ z, const float* __restrict__ wt,
            float* __restrict__ part, int kch) {
    __shared__ __align__(1024) float wlds[256 * 64];  // up to 64 KB (kch<=256)

    int tid  = threadIdx.x;
    int lane = tid & 63;
    int wv   = tid >> 6;         // 0..3
    int d0   = wv * 16;
    int n0   = blockIdx.x * 256; // 256 rows (t) per block
    int ks   = blockIdx.y;
    int c0   = ks * kch;
    int b    = n0 >> 11;
    int t0   = (n0 & 2047) + lane * 4;

    {
        const f32x4* wsrc = (const f32x4*)(wt + (size_t)c0 * DCB);
        int ncalls = kch / 16;
        for (int k = 0; k < ncalls; ++k) {
            int ub = k * 256 + wv * 64;
            __builtin_amdgcn_global_load_lds((gas_ptr)(wsrc + ub + lane),
                                             (las_ptr)((f32x4*)wlds + ub), 16, 0, 0);
        }
    }
    asm volatile("s_waitcnt vmcnt(0)" ::: "memory");
    __syncthreads();

    const float* zp = z + (size_t)b * (DIN * TT) + (size_t)c0 * TT + t0;

    f32x4 acc[4][4];
    #pragma unroll
    for (int i = 0; i < 4; ++i)
        #pragma unroll
        for (int j = 0; j < 4; ++j) acc[i][j] = (f32x4)0.0f;

    #pragma unroll 8
    for (int c = 0; c < kch; ++c) {
        f32x4 zv = *(const f32x4*)(zp + (size_t)c * TT);
        const f32x4* wr = (const f32x4*)&wlds[c * DCB + d0];
        f32x4 w0 = wr[0], w1 = wr[1], w2 = wr[2], w3 = wr[3];
        #pragma unroll
        for (int tq = 0; tq < 4; ++tq) {
            float zs = zv[tq];
            acc[tq][0] += w0 * zs;
            acc[tq][1] += w1 * zs;
            acc[tq][2] += w2 * zs;
            acc[tq][3] += w3 * zs;
        }
    }

    float* pp = part + ((size_t)ks * NN + n0 + lane * 4) * DCB + d0;
    #pragma unroll
    for (int tq = 0; tq < 4; ++tq) {
        f32x4* dst = (f32x4*)(pp + (size_t)tq * DCB);
        dst[0] = acc[tq][0];
        dst[1] = acc[tq][1];
        dst[2] = acc[tq][2];
        dst[3] = acc[tq][3];
    }
}

// ---------------------------------------------------------------------------
// Kernel 3b: combine partials + bias, L2-normalize rows, emit split-f16.
// ---------------------------------------------------------------------------
__global__ void __launch_bounds__(256) k_combine(const float* __restrict__ part,
                                                 const float* __restrict__ bias,
                                                 _Float16* __restrict__ eh,
                                                 _Float16* __restrict__ el,
                                                 int ksplit) {
    int gid = blockIdx.x * 256 + threadIdx.x;  // 0..131071
    int n   = gid >> 3;
    int d0  = (gid & 7) * 8;

    float ze[8];
    #pragma unroll
    for (int j = 0; j < 8; ++j) ze[j] = bias[d0 + j];

    for (int ks = 0; ks < ksplit; ++ks) {
        const float4* pp = (const float4*)(part + ((size_t)ks * NN + n) * DCB + d0);
        float4 p0 = pp[0], p1 = pp[1];
        ze[0] += p0.x; ze[1] += p0.y; ze[2] += p0.z; ze[3] += p0.w;
        ze[4] += p1.x; ze[5] += p1.y; ze[6] += p1.z; ze[7] += p1.w;
    }

    float ss = 0.0f;
    #pragma unroll
    for (int j = 0; j < 8; ++j) ss = fmaf(ze[j], ze[j], ss);
    ss += __shfl_xor(ss, 1, 64);
    ss += __shfl_xor(ss, 2, 64);
    ss += __shfl_xor(ss, 4, 64);
    float den = fmaxf(sqrtf(ss), EPSN);

    half8 vh, vl;
    #pragma unroll
    for (int j = 0; j < 8; ++j) {
        float x = ze[j] / den;
        _Float16 h = (_Float16)x;
        vh[j] = h;
        vl[j] = (_Float16)((x - (float)h) * 2048.0f);
    }
    *(half8*)&eh[(size_t)n * DCB + d0] = vh;
    *(half8*)&el[(size_t)n * DCB + d0] = vl;
}

// ---------------------------------------------------------------------------
// Kernel 4: fused split-f16 MFMA GEMM + argmax (R10 exact — measured best:
// ~74 us. TCODES=32, 2 LDS buffers, __syncthreads per tile, c2 from global,
// Ahh 4-deep + Amid 8-deep chains).
// ---------------------------------------------------------------------------
__global__ void __launch_bounds__(256) k_distmax(const _Float16* __restrict__ eh,
                                                 const _Float16* __restrict__ el,
                                                 const _Float16* __restrict__ chg,
                                                 const _Float16* __restrict__ clg,
                                                 const float* __restrict__ c2,
                                                 float* __restrict__ pscore,
                                                 int* __restrict__ pidx) {
    __shared__ __align__(1024) char smem[2][2][4096];  // [buf][h/l][4KB tile]

    int tid  = threadIdx.x;
    int w    = tid >> 6;
    int lane = tid & 63;
    int rr   = lane & 31;   // A: row slot / B: code slot / C: col
    int hhf  = lane >> 5;   // k-half selector
    int chunk = blockIdx.y;
    int v0   = chunk * CPCHUNK;
    int m0   = blockIdx.x * 128 + w * 32;

    // ---- A-frags: en row (m0+rr), split hi/lo, 4 K-chunks each ----
    const char* ehp = (const char*)(eh + (size_t)(m0 + rr) * DCB) + hhf * 16;
    const char* elp = (const char*)(el + (size_t)(m0 + rr) * DCB) + hhf * 16;
    half8 ah0 = *(const half8*)(ehp +  0), ah1 = *(const half8*)(ehp + 32);
    half8 ah2 = *(const half8*)(ehp + 64), ah3 = *(const half8*)(ehp + 96);
    half8 al0 = *(const half8*)(elp +  0), al1 = *(const half8*)(elp + 32);
    half8 al2 = *(const half8*)(elp + 64), al3 = *(const half8*)(elp + 96);
    asm volatile("" : "+v"(ah0), "+v"(ah1), "+v"(ah2), "+v"(ah3),
                      "+v"(al0), "+v"(al1), "+v"(al2), "+v"(al3));

    // ---- staging: swizzled global source -> linear LDS dest ----
    #define STAGE(b, t)                                                          \
    {                                                                            \
        const char* chs = (const char*)chg + ((size_t)(v0 + (t) * 32)) * 128;    \
        const char* cls = (const char*)clg + ((size_t)(v0 + (t) * 32)) * 128;    \
        _Pragma("unroll")                                                        \
        for (int j = 0; j < 2; ++j) {                                            \
            int cc   = w * 2 + j;                                                \
            int prt  = cc & 3;                                                   \
            int lin  = prt * 1024 + (lane << 4);                                 \
            int so   = lin ^ (((lin >> 7) & 7) << 4);                            \
            const char* gs = (cc < 4 ? chs : cls) + so;                          \
            __builtin_amdgcn_global_load_lds((gas_ptr)gs,                        \
                (las_ptr)&smem[b][cc >= 4][prt * 1024], 16, 0, 0);               \
        }                                                                        \
    }

    STAGE(0, 0);

    f32x16 kz;
    f32x16 best;
    i32x16 bidx;
    #pragma unroll
    for (int i = 0; i < 16; ++i) { kz[i] = 0.0f; best[i] = -INFINITY; bidx[i] = 0; }

    asm volatile("s_waitcnt vmcnt(0)" ::: "memory");
    __syncthreads();

    int lin0 = rr * 128 + hhf * 16;  // frag byte base within tile

    for (int t = 0; t < TSTEPS; ++t) {
        int cur = t & 1;
        if (t + 1 < TSTEPS) STAGE(cur ^ 1, t + 1);

        int   vcode = v0 + t * 32 + rr;
        float c2v   = c2[vcode];

        #define SWZ(x) ((x) ^ ((((x) >> 7) & 7) << 4))
        half8 bh0 = *(const half8*)&smem[cur][0][SWZ(lin0 +  0)];
        half8 bh1 = *(const half8*)&smem[cur][0][SWZ(lin0 + 32)];
        half8 bh2 = *(const half8*)&smem[cur][0][SWZ(lin0 + 64)];
        half8 bh3 = *(const half8*)&smem[cur][0][SWZ(lin0 + 96)];
        half8 bl0 = *(const half8*)&smem[cur][1][SWZ(lin0 +  0)];
        half8 bl1 = *(const half8*)&smem[cur][1][SWZ(lin0 + 32)];
        half8 bl2 = *(const half8*)&smem[cur][1][SWZ(lin0 + 64)];
        half8 bl3 = *(const half8*)&smem[cur][1][SWZ(lin0 + 96)];
        #undef SWZ

        f32x16 Ahh, Amid;
        Ahh  = __builtin_amdgcn_mfma_f32_32x32x16_f16(ah0, bh0, kz, 0, 0, 0);
        Amid = __builtin_amdgcn_mfma_f32_32x32x16_f16(ah0, bl0, kz, 0, 0, 0);
        Amid = __builtin_amdgcn_mfma_f32_32x32x16_f16(al0, bh0, Amid, 0, 0, 0);
        Ahh  = __builtin_amdgcn_mfma_f32_32x32x16_f16(ah1, bh1, Ahh, 0, 0, 0);
        Amid = __builtin_amdgcn_mfma_f32_32x32x16_f16(ah1, bl1, Amid, 0, 0, 0);
        Amid = __builtin_amdgcn_mfma_f32_32x32x16_f16(al1, bh1, Amid, 0, 0, 0);
        Ahh  = __builtin_amdgcn_mfma_f32_32x32x16_f16(ah2, bh2, Ahh, 0, 0, 0);
        Amid = __builtin_amdgcn_mfma_f32_32x32x16_f16(ah2, bl2, Amid, 0, 0, 0);
        Amid = __builtin_amdgcn_mfma_f32_32x32x16_f16(al2, bh2, Amid, 0, 0, 0);
        Ahh  = __builtin_amdgcn_mfma_f32_32x32x16_f16(ah3, bh3, Ahh, 0, 0, 0);
        Amid = __builtin_amdgcn_mfma_f32_32x32x16_f16(ah3, bl3, Amid, 0, 0, 0);
        Amid = __builtin_amdgcn_mfma_f32_32x32x16_f16(al3, bh3, Amid, 0, 0, 0);

        #pragma unroll
        for (int i = 0; i < 16; ++i) {
            float dot = fmaf(Amid[i], 4.8828125e-4f, Ahh[i]);  // hh + mid/2048
            float s   = fmaf(2.0f, dot, -c2v);                 // 2*dot - cn2
            bool  g   = s > best[i];
            best[i]   = g ? s : best[i];
            bidx[i]   = g ? vcode : bidx[i];
        }

        asm volatile("s_waitcnt vmcnt(0)" ::: "memory");
        __syncthreads();
    }
    #undef STAGE

    // ---- cross-lane argmax per output row (32 lanes share a row-set) ----
    #pragma unroll
    for (int i = 0; i < 16; ++i) {
        float bv = best[i];
        int   bi = bidx[i];
        #pragma unroll
        for (int off = 1; off < 32; off <<= 1) {
            float ob = __shfl_xor(bv, off, 64);
            int   oi = __shfl_xor(bi, off, 64);
            if (ob > bv || (ob == bv && oi < bi)) { bv = ob; bi = oi; }
        }
        if (rr == 0) {
            int row = m0 + (i & 3) + 8 * (i >> 2) + 4 * hhf;
            pscore[(size_t)chunk * NN + row] = bv;
            pidx  [(size_t)chunk * NN + row] = bi;
        }
    }
}

// ---------------------------------------------------------------------------
// Kernel 5: combine per-chunk winners (ascending chunk order preserves
// first-index tie-break). Output dtype is int32.
// ---------------------------------------------------------------------------
__global__ void __launch_bounds__(256) k_reduce(const float* __restrict__ pscore,
                                                const int* __restrict__ pidx,
                                                int* __restrict__ out) {
    int n = blockIdx.x * 256 + threadIdx.x;
    float best = -INFINITY;
    int   bi   = 0;
    #pragma unroll
    for (int c = 0; c < DSPLIT; ++c) {
        float s = pscore[(size_t)c * NN + n];
        int  id = pidx [(size_t)c * NN + n];
        if (s > best) { best = s; bi = id; }
    }
    out[n] = bi;
}

// ---------------------------------------------------------------------------
extern "C" void kernel_launch(void* const* d_in, const int* in_sizes, int n_in,
                              void* d_out, int out_size, void* d_ws, size_t ws_size,
                              hipStream_t stream) {
    const float* z  = (const float*)d_in[0];  // [8,1024,2048]
    const float* W  = (const float*)d_in[1];  // [64,1024]
    const float* bi = (const float*)d_in[2];  // [64]
    const float* cb = (const float*)d_in[3];  // [8192,64]
    int* out = (int*)d_out;                   // [16384] indices, int32

    char* ws = (char*)d_ws;
    _Float16* ch  = (_Float16*)(ws);                         // 1 MB
    _Float16* cl  = (_Float16*)(ws + 1048576);               // 1 MB
    float*    c2  = (float*)   (ws + 2097152);               // 32 KB
    float*    wt  = (float*)   (ws + 2129920);               // 256 KB
    _Float16* eh  = (_Float16*)(ws + 2392064);               // 2 MB
    _Float16* el  = (_Float16*)(ws + 4489216);               // 2 MB
    float* pscore = (float*)   (ws + 6586368);               // 256 KB
    int*   pidx   = (int*)     (ws + 6848512);               // 256 KB
    float* part   = (float*)   (ws + 7110656);               // 16 or 32 MB

    // Deterministic per-environment: ws_size is fixed, so ksplit is fixed.
    const size_t need8 = 7110656ULL + (size_t)8 * NN * DCB * 4;  // 40,665,088
    int ksplit = (ws_size >= need8) ? 8 : 4;
    int kch    = DIN / ksplit;

    hipLaunchKernelGGL(k_prep_cb,   dim3(VV / 4),          dim3(256), 0, stream, cb, ch, cl, c2);
    hipLaunchKernelGGL(k_prep_wt,   dim3(DIN * DCB / 256), dim3(256), 0, stream, W, wt);
    hipLaunchKernelGGL(k_gemm_part, dim3(NN / 256, ksplit), dim3(256), 0, stream, z, wt, part, kch);
    hipLaunchKernelGGL(k_combine,   dim3(NN * 8 / 256),    dim3(256), 0, stream, part, bi, eh, el, ksplit);
    hipLaunchKernelGGL(k_distmax,   dim3(NN / 128, DSPLIT), dim3(256), 0, stream,
                       eh, el, ch, cl, c2, pscore, pidx);
    hipLaunchKernelGGL(k_reduce,    dim3(NN / 256),        dim3(256), 0, stream, pscore, pidx, out);
}